// Round 1
// 269.541 us; speedup vs baseline: 1.0288x; 1.0288x over previous
//
#include <hip/hip_runtime.h>

// B=8192, A=8, OBS=128, NACT=32, H=256, D=64 ; N = 65536 rows
typedef __attribute__((ext_vector_type(8))) short bf16x8;   // 8 bf16 (4 VGPRs)
typedef __attribute__((ext_vector_type(4))) float f32x4;

#define MFMA(A, B, C) __builtin_amdgcn_mfma_f32_16x16x32_bf16((A), (B), (C), 0, 0, 0)

// ---- ws byte offsets: weights pre-split to bf16 hi/lo planes, [out][k] layout ----
#define OFF_TB    0          // f32 [32]   folded t bias
#define OFF_WT_H  128        // bf16 [32][256]  Mt = SCALE*wk^T*wq
#define OFF_WT_L  16512
#define OFF_WHV_H 32896      // bf16 [64][256]  wv1 h-part
#define OFF_WHV_L 65664
#define OFF_WA_H  98432      // bf16 [64][32]   wv1 action-part
#define OFF_WA_L  102528     // end 106624

// ---- LDS layout (bytes), total 29184 -> 5 blocks LDS-wise, 4 by VGPR (16 waves/CU) ----
// (was 46592 -> 3 blocks/CU; dropped W2 staging + T tile: T now lives in registers)
#define SM_HV   0        // f32 [64][68]   17408
#define SM_AT   17408    // f32 [64][8]     2048  (attn probs, row-major)
#define SM_SS   19456    // bf16 [64][76]   9728
#define SM_TOT  29184

__device__ __forceinline__ unsigned short f2bf(float v) {   // RNE
    unsigned u = __builtin_bit_cast(unsigned, v);
    return (unsigned short)((u + 0x7fffu + ((u >> 16) & 1u)) >> 16);
}
__device__ __forceinline__ float bf2f(unsigned short b) {
    return __builtin_bit_cast(float, ((unsigned)b) << 16);
}
__device__ __forceinline__ ushort2 splitf(float v) {        // (hi, lo residual)
    unsigned short h = f2bf(v);
    unsigned short l = f2bf(v - bf2f(h));
    return make_ushort2(h, l);
}
__device__ __forceinline__ void split8(float4 a, float4 b, bf16x8& hi, bf16x8& lo) {
    float v[8] = {a.x, a.y, a.z, a.w, b.x, b.y, b.z, b.w};
    bf16x8 H, L;
#pragma unroll
    for (int i = 0; i < 8; ++i) {
        ushort2 s = splitf(v[i]);
        H[i] = (short)s.x;
        L[i] = (short)s.y;
    }
    hi = H; lo = L;
}

// ---------------------------------------------------------------------------
// setup: fold Mt = SCALE*wk^T*wq (+bias), split all weights into bf16 hi/lo
// planes in fragment-native [out][k] layout. wk_b dropped (softmax-invariant,
// diagonal masked — verified round 1).
// ---------------------------------------------------------------------------
__global__ __launch_bounds__(256) void k_setup(const float* __restrict__ wq_w,
                                               const float* __restrict__ wq_b,
                                               const float* __restrict__ wk_w,
                                               const float* __restrict__ wv1,
                                               char* __restrict__ ws) {
    int gid = blockIdx.x * 256 + threadIdx.x;
    if (gid < 8192) {                              // Mt[k][c]
        int k = gid >> 8, c = gid & 255;
        float acc = 0.f;
#pragma unroll 8
        for (int d = 0; d < 64; ++d) acc = fmaf(wk_w[d * 32 + k], wq_w[d * 256 + c], acc);
        ushort2 s = splitf(0.125f * acc);
        ((unsigned short*)(ws + OFF_WT_H))[gid] = s.x;
        ((unsigned short*)(ws + OFF_WT_L))[gid] = s.y;
    } else if (gid < 24576) {                      // wv1 h-part [d][c]
        int i = gid - 8192;
        ushort2 s = splitf(wv1[(i >> 8) * 288 + (i & 255)]);
        ((unsigned short*)(ws + OFF_WHV_H))[i] = s.x;
        ((unsigned short*)(ws + OFF_WHV_L))[i] = s.y;
    } else if (gid < 26624) {                      // wv1 action-part [d][k]
        int i = gid - 24576;
        ushort2 s = splitf(wv1[(i >> 5) * 288 + 256 + (i & 31)]);
        ((unsigned short*)(ws + OFF_WA_H))[i] = s.x;
        ((unsigned short*)(ws + OFF_WA_L))[i] = s.y;
    } else if (gid < 26656) {                      // tb
        int k = gid - 26624;
        float b = 0.f;
#pragma unroll 8
        for (int d = 0; d < 64; ++d) b = fmaf(wk_w[d * 32 + k], wq_b[d], b);
        ((float*)(ws + OFF_TB))[k] = 0.125f * b;
    }
}

// ---------------------------------------------------------------------------
// Fused, block = 64 rows (8 batches). Split-bf16 MFMA (AhBh+AhBl+AlBh).
// This round: latency-bound fix. LDS 46.6K->29.2K (4 blocks/CU), barriers
// 4->2 (scores+softmax fully in-register via t-fragment quad-reduce),
// explicit 8-deep activation preloads for MLP, coalesced full-line C-writes.
// ---------------------------------------------------------------------------
__global__ __launch_bounds__(256, 4) void fused(
    const float* __restrict__ o, const float* __restrict__ onx,
    const float* __restrict__ h, const float* __restrict__ act,
    const float* __restrict__ wv1b, const float* __restrict__ wv2,
    const float* __restrict__ wv2b, const char* __restrict__ ws,
    float* __restrict__ out)
{
    __shared__ __align__(16) char sm[SM_TOT];
    float* HV = (float*)(sm + SM_HV);
    float* AT = (float*)(sm + SM_AT);
    short* SS = (short*)(sm + SM_SS);

    const int tid  = threadIdx.x;
    const int lane = tid & 63;
    const int wid  = tid >> 6;
    const int l15  = lane & 15;
    const int quad = lane >> 4;
    const int n0   = blockIdx.x * 64;

    const f32x4 zv = {0.f, 0.f, 0.f, 0.f};
    f32x4 acc_hv[4] = {zv, zv, zv, zv};
    f32x4 acc_t[2]  = {zv, zv};

    const int myrow = n0 + wid * 16 + l15;    // phase-A fragment row of this lane

    // ---- Phase A-x: preload all 8 chunks (8KB/wave in flight), then MFMA ----
    float4 xa[8], xb[8];
#pragma unroll
    for (int ch = 0; ch < 8; ++ch) {
        const float* src = (ch < 4)
            ? o   + (size_t)myrow * 128 + ch * 32 + quad * 8
            : onx + (size_t)myrow * 128 + (ch - 4) * 32 + quad * 8;
        xa[ch] = ((const float4*)src)[0];
        xb[ch] = ((const float4*)src)[1];
    }
#pragma unroll
    for (int ch = 0; ch < 8; ++ch) {
        bf16x8 Bh, Bl;
        split8(xa[ch], xb[ch], Bh, Bl);
#pragma unroll
        for (int mt = 0; mt < 2; ++mt) {
            int off = ((mt * 16 + l15) * 256 + ch * 32 + quad * 8) * 2;
            bf16x8 Ah = *(const bf16x8*)(ws + OFF_WT_H + off);
            bf16x8 Al = *(const bf16x8*)(ws + OFF_WT_L + off);
            acc_t[mt] = MFMA(Ah, Bh, acc_t[mt]);
            acc_t[mt] = MFMA(Ah, Bl, acc_t[mt]);
            acc_t[mt] = MFMA(Al, Bh, acc_t[mt]);
        }
    }
    // ---- Phase A-h: preload all 8 chunks, then MFMA ----
#pragma unroll
    for (int ch = 0; ch < 8; ++ch) {
        const float* src = h + (size_t)myrow * 256 + ch * 32 + quad * 8;
        xa[ch] = ((const float4*)src)[0];
        xb[ch] = ((const float4*)src)[1];
    }
#pragma unroll
    for (int ch = 0; ch < 8; ++ch) {
        bf16x8 Bh, Bl;
        split8(xa[ch], xb[ch], Bh, Bl);
#pragma unroll
        for (int mt = 0; mt < 4; ++mt) {
            int off = ((mt * 16 + l15) * 256 + ch * 32 + quad * 8) * 2;
            bf16x8 Ah = *(const bf16x8*)(ws + OFF_WHV_H + off);
            bf16x8 Al = *(const bf16x8*)(ws + OFF_WHV_L + off);
            acc_hv[mt] = MFMA(Ah, Bh, acc_hv[mt]);
            acc_hv[mt] = MFMA(Ah, Bl, acc_hv[mt]);
            acc_hv[mt] = MFMA(Al, Bh, acc_hv[mt]);
        }
    }

    // ---- scores act preload (issued early; latency hides under HV epilogue) ----
    // lane owns its fragment row; cols quad*4 (mt0) and 16+quad*4 (mt1)
    const float* arow = act + (size_t)myrow * 256;
    float4 av0[8], av1[8];
#pragma unroll
    for (int j = 0; j < 8; ++j) {
        av0[j] = *(const float4*)(arow + j * 32 + quad * 4);
        av1[j] = *(const float4*)(arow + j * 32 + 16 + quad * 4);
    }

    // ---- epilogue A: HV to LDS (C/D layout: col=l15 -> row n, row=quad*4+reg -> d) ----
    {
        int erow = wid * 16 + l15;
#pragma unroll
        for (int mt = 0; mt < 4; ++mt) {
            int d0 = mt * 16 + quad * 4;
            float4 b = *(const float4*)&wv1b[d0];
            f32x4 a = acc_hv[mt];
            *(float4*)&HV[erow * 68 + d0] =
                make_float4(a[0] + b.x, a[1] + b.y, a[2] + b.z, a[3] + b.w);
        }
    }

    // ---- scores + softmax fully in-register (no T tile, no extra barriers) ----
    // t8 = this lane's 8 t-cols {mt*16+quad*4+r}; quad-reduce completes the
    // 32-col dot; softmax over j is row-local -> per-lane.
    {
        float t8[8];
        const float* tb = (const float*)(ws + OFF_TB);
#pragma unroll
        for (int mt = 0; mt < 2; ++mt) {
            float4 b = *(const float4*)&tb[mt * 16 + quad * 4];
            t8[mt * 4 + 0] = acc_t[mt][0] + b.x;
            t8[mt * 4 + 1] = acc_t[mt][1] + b.y;
            t8[mt * 4 + 2] = acc_t[mt][2] + b.z;
            t8[mt * 4 + 3] = acc_t[mt][3] + b.w;
        }
        float sc[8];
#pragma unroll
        for (int j = 0; j < 8; ++j) {
            float s = 0.f;
            s = fmaf(t8[0], av0[j].x, s);
            s = fmaf(t8[1], av0[j].y, s);
            s = fmaf(t8[2], av0[j].z, s);
            s = fmaf(t8[3], av0[j].w, s);
            s = fmaf(t8[4], av1[j].x, s);
            s = fmaf(t8[5], av1[j].y, s);
            s = fmaf(t8[6], av1[j].z, s);
            s = fmaf(t8[7], av1[j].w, s);
            sc[j] = s;
        }
#pragma unroll
        for (int j = 0; j < 8; ++j) {        // sum partials across the 4 quads
            sc[j] += __shfl_xor(sc[j], 16);
            sc[j] += __shfl_xor(sc[j], 32);
        }
        const int diag = l15 & 7;            // row mod 8 (n0, wid*16 are 8-aligned)
        float mx = -1e30f;
#pragma unroll
        for (int j = 0; j < 8; ++j) if (j != diag) mx = fmaxf(mx, sc[j]);
        float ex[8], sum = 0.f;
#pragma unroll
        for (int j = 0; j < 8; ++j) {
            ex[j] = (j == diag) ? 0.f : __expf(sc[j] - mx);
            sum += ex[j];
        }
        float inv = 1.f / sum;
        if (quad == 0) {                     // one writer per row
            int row = wid * 16 + l15;
            *(float4*)&AT[row * 8] =
                make_float4(ex[0] * inv, ex[1] * inv, ex[2] * inv, ex[3] * inv);
            *(float4*)&AT[row * 8 + 4] =
                make_float4(ex[4] * inv, ex[5] * inv, ex[6] * inv, ex[7] * inv);
        }
    }

    // hoist phase-B A-frags (latency hidden under the barrier)
    bf16x8 WAh[4], WAl[4];
#pragma unroll
    for (int mt = 0; mt < 4; ++mt) {
        int off = ((mt * 16 + l15) * 32 + quad * 8) * 2;
        WAh[mt] = *(const bf16x8*)(ws + OFF_WA_H + off);
        WAl[mt] = *(const bf16x8*)(ws + OFF_WA_L + off);
    }
    __syncthreads();                               // barrier 1: HV + AT visible

    // ---- Phase B: act fragments direct from global, 4-deep preload groups ----
    // njr = (local row nb, attended j); ha = Wv1a·a via MFMA, then
    // s[nb][d] = sum_j attn*relu(hv+ha) via shfl-reduce over the 8 j-lanes.
#pragma unroll
    for (int half = 0; half < 2; ++half) {
        float4 bv0[4], bv1[4];
        int nbs[4], js[4];
#pragma unroll
        for (int ii = 0; ii < 4; ++ii) {
            int g   = half * 2 + (ii >> 1);
            int nt  = ii & 1;
            int njr = wid * 32 + nt * 16 + l15;
            int nb  = g * 16 + (njr >> 3);
            int j   = njr & 7;
            const float* ap = act + (size_t)(n0 + nb) * 256 + j * 32 + quad * 8;
            bv0[ii] = ((const float4*)ap)[0];
            bv1[ii] = ((const float4*)ap)[1];
            nbs[ii] = nb; js[ii] = j;
        }
#pragma unroll
        for (int ii = 0; ii < 4; ++ii) {
            int nb = nbs[ii], j = js[ii];
            bf16x8 Bh, Bl;
            split8(bv0[ii], bv1[ii], Bh, Bl);
            f32x4 accB[4] = {zv, zv, zv, zv};
#pragma unroll
            for (int mt = 0; mt < 4; ++mt) {
                accB[mt] = MFMA(WAh[mt], Bh, accB[mt]);
                accB[mt] = MFMA(WAh[mt], Bl, accB[mt]);
                accB[mt] = MFMA(WAl[mt], Bh, accB[mt]);
            }
            int hrow = (nb & ~7) + j;              // h_rep row = batch base + j
            float at = AT[nb * 8 + j];
#pragma unroll
            for (int mt = 0; mt < 4; ++mt) {
                int d0 = mt * 16 + quad * 4;
                float4 hv4 = *(const float4*)&HV[hrow * 68 + d0];
                float r0 = at * fmaxf(accB[mt][0] + hv4.x, 0.f);
                float r1 = at * fmaxf(accB[mt][1] + hv4.y, 0.f);
                float r2 = at * fmaxf(accB[mt][2] + hv4.z, 0.f);
                float r3 = at * fmaxf(accB[mt][3] + hv4.w, 0.f);
#pragma unroll
                for (int m = 1; m <= 4; m <<= 1) {
                    r0 += __shfl_xor(r0, m);
                    r1 += __shfl_xor(r1, m);
                    r2 += __shfl_xor(r2, m);
                    r3 += __shfl_xor(r3, m);
                }
                if (j == 0)
                    *(ushort4*)&SS[nb * 76 + d0] =
                        make_ushort4(f2bf(r0), f2bf(r1), f2bf(r2), f2bf(r3));
            }
        }
    }
    __syncthreads();                               // barrier 2: SS visible

    // ---- Wv2: wave owns 16 rows x all 32 e; lane = (row=l15, e-slice=quad*8) ----
    // Full 128B-line output writes (was 16B/line partial). wv2 from global:
    // 8KB shared by all blocks, L1-hot; 4 unique addrs/instr (quad broadcast).
    {
        int row = wid * 16 + l15;
        float s[64];
#pragma unroll
        for (int q = 0; q < 16; ++q) {             // quads read same addr -> broadcast
            ushort4 u = *(const ushort4*)&SS[row * 76 + q * 4];
            s[q*4+0] = bf2f(u.x); s[q*4+1] = bf2f(u.y);
            s[q*4+2] = bf2f(u.z); s[q*4+3] = bf2f(u.w);
        }
        float qa[8];
#pragma unroll
        for (int e0 = 0; e0 < 8; ++e0) qa[e0] = wv2b[quad * 8 + e0];
#pragma unroll
        for (int d4 = 0; d4 < 16; ++d4) {
#pragma unroll
            for (int e0 = 0; e0 < 8; ++e0) {
                float4 w = *(const float4*)&wv2[(quad * 8 + e0) * 64 + d4 * 4];
                qa[e0] = fmaf(w.x, s[d4*4+0], qa[e0]);
                qa[e0] = fmaf(w.y, s[d4*4+1], qa[e0]);
                qa[e0] = fmaf(w.z, s[d4*4+2], qa[e0]);
                qa[e0] = fmaf(w.w, s[d4*4+3], qa[e0]);
            }
        }
        float* op = out + (size_t)(n0 + row) * 32 + quad * 8;
        ((float4*)op)[0] = make_float4(qa[0], qa[1], qa[2], qa[3]);
        ((float4*)op)[1] = make_float4(qa[4], qa[5], qa[6], qa[7]);
    }
}

extern "C" void kernel_launch(void* const* d_in, const int* in_sizes, int n_in,
                              void* d_out, int out_size, void* d_ws, size_t ws_size,
                              hipStream_t stream) {
    const float* o     = (const float*)d_in[0];
    const float* onx   = (const float*)d_in[1];
    const float* h     = (const float*)d_in[2];
    const float* act   = (const float*)d_in[3];
    const float* wq_w  = (const float*)d_in[4];
    const float* wq_b  = (const float*)d_in[5];
    const float* wk_w  = (const float*)d_in[6];
    // d_in[7] = wk_b unused (softmax-invariant, diagonal masked)
    const float* wv1_w = (const float*)d_in[8];
    const float* wv1_b = (const float*)d_in[9];
    const float* wv2_w = (const float*)d_in[10];
    const float* wv2_b = (const float*)d_in[11];
    float* out = (float*)d_out;
    char* ws   = (char*)d_ws;   // needs ~105 KB

    k_setup<<<105, 256, 0, stream>>>(wq_w, wq_b, wk_w, wv1_w, ws);
    fused<<<1024, 256, 0, stream>>>(o, onx, h, act, wv1_b, wv2_w, wv2_b, ws, out);
}

// Round 4
// 251.250 us; speedup vs baseline: 1.1038x; 1.0728x over previous
//
#include <hip/hip_runtime.h>
#include <hip/hip_bf16.h>

// B=8192, A=8, OBS=128, NACT=32, H=256, D=64 ; N = 65536 rows
typedef __attribute__((ext_vector_type(8))) short bf16x8;   // 8 bf16 (4 VGPRs)
typedef __attribute__((ext_vector_type(4))) float f32x4;

#define MFMA(A, B, C) __builtin_amdgcn_mfma_f32_16x16x32_bf16((A), (B), (C), 0, 0, 0)

// ---- ws byte offsets: weights pre-split to bf16 hi/lo planes, [out][k] layout ----
#define OFF_TB    0          // f32 [32]   folded t bias
#define OFF_WT_H  128        // bf16 [32][256]  Mt = SCALE*wk^T*wq
#define OFF_WT_L  16512
#define OFF_WHV_H 32896      // bf16 [64][256]  wv1 h-part
#define OFF_WHV_L 65664
#define OFF_WA_H  98432      // bf16 [64][32]   wv1 action-part
#define OFF_WA_L  102528     // end 106624

// ---- LDS (bytes), total 7168 -> LDS allows 22 blk/CU; grid-limited 16 waves/CU ----
// Single-wave workgroup (64 thr, 16 rows): barriers are intra-wave (cheap), all
// resident waves fully independent -> latency hiding via wave staggering.
// SS stride = 72 ushorts (>= 64 d-values + pad). Round-3 bug was stride 40:
// rows overlapped (d 40..63 of row nb == d 0..23 of row nb+1) -> race.
#define SM_HV   0        // f32 [16][68]    4352
#define SM_AT   4352     // f32 [16][8]      512
#define SM_SS   4864     // bf16 [16][72]   2304
#define SM_TOT  7168

__device__ __forceinline__ unsigned short f2bf(float v) {   // RNE (setup only)
    unsigned u = __builtin_bit_cast(unsigned, v);
    return (unsigned short)((u + 0x7fffu + ((u >> 16) & 1u)) >> 16);
}
__device__ __forceinline__ float bf2f(unsigned short b) {
    return __builtin_bit_cast(float, ((unsigned)b) << 16);
}
__device__ __forceinline__ ushort2 splitf(float v) {        // (hi, lo residual)
    unsigned short h = f2bf(v);
    unsigned short l = f2bf(v - bf2f(h));
    return make_ushort2(h, l);
}

// __hip_bfloat162 -> u32 reinterpret (bit_cast rejects non-trivially-copyable)
__device__ __forceinline__ unsigned as_u32(__hip_bfloat162 v) {
    unsigned u;
    __builtin_memcpy(&u, &v, sizeof(u));
    return u;
}

// fast split via packed f32->bf16 convert (RNE, identical numerics to f2bf)
__device__ __forceinline__ void split2(float x, float y, unsigned& h, unsigned& l) {
    __hip_bfloat162 h2 = __float22bfloat162_rn(make_float2(x, y));
    float2 hf = __bfloat1622float2(h2);
    __hip_bfloat162 l2 = __float22bfloat162_rn(make_float2(x - hf.x, y - hf.y));
    h = as_u32(h2);
    l = as_u32(l2);
}
__device__ __forceinline__ void split8(float4 a, float4 b, bf16x8& hi, bf16x8& lo) {
    uint4 H, L;
    split2(a.x, a.y, H.x, L.x);
    split2(a.z, a.w, H.y, L.y);
    split2(b.x, b.y, H.z, L.z);
    split2(b.z, b.w, H.w, L.w);
    hi = __builtin_bit_cast(bf16x8, H);
    lo = __builtin_bit_cast(bf16x8, L);
}
__device__ __forceinline__ unsigned pk2(float x, float y) {
    return as_u32(__float22bfloat162_rn(make_float2(x, y)));
}

// ---------------------------------------------------------------------------
// setup: fold Mt = SCALE*wk^T*wq (+bias), split all weights into bf16 hi/lo
// planes in fragment-native [out][k] layout. wk_b dropped (softmax-invariant,
// diagonal masked — verified round 1).
// ---------------------------------------------------------------------------
__global__ __launch_bounds__(256) void k_setup(const float* __restrict__ wq_w,
                                               const float* __restrict__ wq_b,
                                               const float* __restrict__ wk_w,
                                               const float* __restrict__ wv1,
                                               char* __restrict__ ws) {
    int gid = blockIdx.x * 256 + threadIdx.x;
    if (gid < 8192) {                              // Mt[k][c]
        int k = gid >> 8, c = gid & 255;
        float acc = 0.f;
#pragma unroll 8
        for (int d = 0; d < 64; ++d) acc = fmaf(wk_w[d * 32 + k], wq_w[d * 256 + c], acc);
        ushort2 s = splitf(0.125f * acc);
        ((unsigned short*)(ws + OFF_WT_H))[gid] = s.x;
        ((unsigned short*)(ws + OFF_WT_L))[gid] = s.y;
    } else if (gid < 24576) {                      // wv1 h-part [d][c]
        int i = gid - 8192;
        ushort2 s = splitf(wv1[(i >> 8) * 288 + (i & 255)]);
        ((unsigned short*)(ws + OFF_WHV_H))[i] = s.x;
        ((unsigned short*)(ws + OFF_WHV_L))[i] = s.y;
    } else if (gid < 26624) {                      // wv1 action-part [d][k]
        int i = gid - 24576;
        ushort2 s = splitf(wv1[(i >> 5) * 288 + 256 + (i & 31)]);
        ((unsigned short*)(ws + OFF_WA_H))[i] = s.x;
        ((unsigned short*)(ws + OFF_WA_L))[i] = s.y;
    } else if (gid < 26656) {                      // tb
        int k = gid - 26624;
        float b = 0.f;
#pragma unroll 8
        for (int d = 0; d < 64; ++d) b = fmaf(wk_w[d * 32 + k], wq_b[d], b);
        ((float*)(ws + OFF_TB))[k] = 0.125f * b;
    }
}

// ---------------------------------------------------------------------------
// Fused, block = ONE wave = 16 rows (2 batches). Split-bf16 MFMA.
// Round 4 (= round-2 theory, SS-stride-fixed): single-wave workgroups (no
// lockstep, 16 indep waves/CU), cvt_pk-based splits (~3.5x fewer VALU ops),
// Wv2 via MFMA (8 MFMAs replace 512 scalar FMA/lane; W2 frags from global).
// ---------------------------------------------------------------------------
__global__ __launch_bounds__(64, 4) void fused(
    const float* __restrict__ o, const float* __restrict__ onx,
    const float* __restrict__ h, const float* __restrict__ act,
    const float* __restrict__ wv1b, const float* __restrict__ wv2,
    const float* __restrict__ wv2b, const char* __restrict__ ws,
    float* __restrict__ out)
{
    __shared__ __align__(16) char sm[SM_TOT];
    float* HV = (float*)(sm + SM_HV);
    float* AT = (float*)(sm + SM_AT);
    unsigned short* SS = (unsigned short*)(sm + SM_SS);

    const int lane = threadIdx.x;          // 0..63
    const int l15  = lane & 15;
    const int quad = lane >> 4;
    const int n0   = blockIdx.x * 16;
    const int myrow = n0 + l15;            // phase-A fragment row of this lane

    const f32x4 zv = {0.f, 0.f, 0.f, 0.f};
    f32x4 acc_hv[4] = {zv, zv, zv, zv};
    f32x4 acc_t[2]  = {zv, zv};

    // ---- Phase A-x: preload all 8 chunks, then MFMA ----
    float4 xa[8], xb[8];
#pragma unroll
    for (int ch = 0; ch < 8; ++ch) {
        const float* src = (ch < 4)
            ? o   + (size_t)myrow * 128 + ch * 32 + quad * 8
            : onx + (size_t)myrow * 128 + (ch - 4) * 32 + quad * 8;
        xa[ch] = ((const float4*)src)[0];
        xb[ch] = ((const float4*)src)[1];
    }
#pragma unroll
    for (int ch = 0; ch < 8; ++ch) {
        bf16x8 Bh, Bl;
        split8(xa[ch], xb[ch], Bh, Bl);
#pragma unroll
        for (int mt = 0; mt < 2; ++mt) {
            int off = ((mt * 16 + l15) * 256 + ch * 32 + quad * 8) * 2;
            bf16x8 Ah = *(const bf16x8*)(ws + OFF_WT_H + off);
            bf16x8 Al = *(const bf16x8*)(ws + OFF_WT_L + off);
            acc_t[mt] = MFMA(Ah, Bh, acc_t[mt]);
            acc_t[mt] = MFMA(Ah, Bl, acc_t[mt]);
            acc_t[mt] = MFMA(Al, Bh, acc_t[mt]);
        }
    }
    // ---- Phase A-h ----
#pragma unroll
    for (int ch = 0; ch < 8; ++ch) {
        const float* src = h + (size_t)myrow * 256 + ch * 32 + quad * 8;
        xa[ch] = ((const float4*)src)[0];
        xb[ch] = ((const float4*)src)[1];
    }
#pragma unroll
    for (int ch = 0; ch < 8; ++ch) {
        bf16x8 Bh, Bl;
        split8(xa[ch], xb[ch], Bh, Bl);
#pragma unroll
        for (int mt = 0; mt < 4; ++mt) {
            int off = ((mt * 16 + l15) * 256 + ch * 32 + quad * 8) * 2;
            bf16x8 Ah = *(const bf16x8*)(ws + OFF_WHV_H + off);
            bf16x8 Al = *(const bf16x8*)(ws + OFF_WHV_L + off);
            acc_hv[mt] = MFMA(Ah, Bh, acc_hv[mt]);
            acc_hv[mt] = MFMA(Ah, Bl, acc_hv[mt]);
            acc_hv[mt] = MFMA(Al, Bh, acc_hv[mt]);
        }
    }

    // ---- scores act preload (latency hides under HV epilogue) ----
    const float* arow = act + (size_t)myrow * 256;
    float4 av0[8], av1[8];
#pragma unroll
    for (int j = 0; j < 8; ++j) {
        av0[j] = *(const float4*)(arow + j * 32 + quad * 4);
        av1[j] = *(const float4*)(arow + j * 32 + 16 + quad * 4);
    }

    // ---- epilogue A: HV to LDS (col=l15 -> row n, row=quad*4+reg -> d) ----
#pragma unroll
    for (int mt = 0; mt < 4; ++mt) {
        int d0 = mt * 16 + quad * 4;
        float4 b = *(const float4*)&wv1b[d0];
        f32x4 a = acc_hv[mt];
        *(float4*)&HV[l15 * 68 + d0] =
            make_float4(a[0] + b.x, a[1] + b.y, a[2] + b.z, a[3] + b.w);
    }

    // ---- scores + softmax fully in-register ----
    {
        float t8[8];
        const float* tb = (const float*)(ws + OFF_TB);
#pragma unroll
        for (int mt = 0; mt < 2; ++mt) {
            float4 b = *(const float4*)&tb[mt * 16 + quad * 4];
            t8[mt * 4 + 0] = acc_t[mt][0] + b.x;
            t8[mt * 4 + 1] = acc_t[mt][1] + b.y;
            t8[mt * 4 + 2] = acc_t[mt][2] + b.z;
            t8[mt * 4 + 3] = acc_t[mt][3] + b.w;
        }
        float sc[8];
#pragma unroll
        for (int j = 0; j < 8; ++j) {
            float s = 0.f;
            s = fmaf(t8[0], av0[j].x, s);
            s = fmaf(t8[1], av0[j].y, s);
            s = fmaf(t8[2], av0[j].z, s);
            s = fmaf(t8[3], av0[j].w, s);
            s = fmaf(t8[4], av1[j].x, s);
            s = fmaf(t8[5], av1[j].y, s);
            s = fmaf(t8[6], av1[j].z, s);
            s = fmaf(t8[7], av1[j].w, s);
            sc[j] = s;
        }
#pragma unroll
        for (int j = 0; j < 8; ++j) {        // sum partials across the 4 quads
            sc[j] += __shfl_xor(sc[j], 16);
            sc[j] += __shfl_xor(sc[j], 32);
        }
        const int diag = l15 & 7;            // row mod 8 (n0 is 16-aligned)
        float mx = -1e30f;
#pragma unroll
        for (int j = 0; j < 8; ++j) if (j != diag) mx = fmaxf(mx, sc[j]);
        float ex[8], sum = 0.f;
#pragma unroll
        for (int j = 0; j < 8; ++j) {
            ex[j] = (j == diag) ? 0.f : __expf(sc[j] - mx);
            sum += ex[j];
        }
        float inv = 1.f / sum;
        if (quad == 0) {                     // one writer per row
            *(float4*)&AT[l15 * 8] =
                make_float4(ex[0] * inv, ex[1] * inv, ex[2] * inv, ex[3] * inv);
            *(float4*)&AT[l15 * 8 + 4] =
                make_float4(ex[4] * inv, ex[5] * inv, ex[6] * inv, ex[7] * inv);
        }
    }

    // hoist phase-B A-frags
    bf16x8 WAh[4], WAl[4];
#pragma unroll
    for (int mt = 0; mt < 4; ++mt) {
        int off = ((mt * 16 + l15) * 32 + quad * 8) * 2;
        WAh[mt] = *(const bf16x8*)(ws + OFF_WA_H + off);
        WAl[mt] = *(const bf16x8*)(ws + OFF_WA_L + off);
    }
    __syncthreads();                         // intra-wave: HV/AT visible

    // ---- Phase B: 16 rows x 8 j = 128 pairs ----
    // nb = nt*2 + (l15>>3), j = l15&7 (j constant per lane across nt)
    const int jB  = l15 & 7;
    const int nbh = l15 >> 3;
#pragma unroll
    for (int half = 0; half < 2; ++half) {
        float4 bv0[4], bv1[4];
#pragma unroll
        for (int ii = 0; ii < 4; ++ii) {
            int nb = (half * 4 + ii) * 2 + nbh;
            const float* ap = act + (size_t)(n0 + nb) * 256 + jB * 32 + quad * 8;
            bv0[ii] = ((const float4*)ap)[0];
            bv1[ii] = ((const float4*)ap)[1];
        }
#pragma unroll
        for (int ii = 0; ii < 4; ++ii) {
            int nt = half * 4 + ii;
            int nb = nt * 2 + nbh;
            bf16x8 Bh, Bl;
            split8(bv0[ii], bv1[ii], Bh, Bl);
            f32x4 accB[4] = {zv, zv, zv, zv};
#pragma unroll
            for (int mt = 0; mt < 4; ++mt) {
                accB[mt] = MFMA(WAh[mt], Bh, accB[mt]);
                accB[mt] = MFMA(WAh[mt], Bl, accB[mt]);
                accB[mt] = MFMA(WAl[mt], Bh, accB[mt]);
            }
            int hrow = (nb & 8) + jB;        // h_rep row within wave's 16 rows
            float at = AT[nb * 8 + jB];
#pragma unroll
            for (int mt = 0; mt < 4; ++mt) {
                int d0 = mt * 16 + quad * 4;
                float4 hv4 = *(const float4*)&HV[hrow * 68 + d0];
                float r0 = at * fmaxf(accB[mt][0] + hv4.x, 0.f);
                float r1 = at * fmaxf(accB[mt][1] + hv4.y, 0.f);
                float r2 = at * fmaxf(accB[mt][2] + hv4.z, 0.f);
                float r3 = at * fmaxf(accB[mt][3] + hv4.w, 0.f);
#pragma unroll
                for (int m = 1; m <= 4; m <<= 1) {
                    r0 += __shfl_xor(r0, m);
                    r1 += __shfl_xor(r1, m);
                    r2 += __shfl_xor(r2, m);
                    r3 += __shfl_xor(r3, m);
                }
                if (jB == 0)                 // S row nb, d0..d0+3, bf16-packed
                    *(uint2*)&SS[nb * 72 + d0] = make_uint2(pk2(r0, r1), pk2(r2, r3));
            }
        }
    }

    // ---- W2 fragment loads (4KB shared, L2-hot) ----
    float4 wva[4], wvb[4];                   // c = et*2 + kc
#pragma unroll
    for (int c = 0; c < 4; ++c) {
        const float* wp = wv2 + ((c >> 1) * 16 + l15) * 64 + (c & 1) * 32 + quad * 8;
        wva[c] = ((const float4*)wp)[0];
        wvb[c] = ((const float4*)wp)[1];
    }
    __syncthreads();                         // intra-wave: SS visible

    // ---- Wv2 via MFMA: out[16x32] = S[16x64] . W2^T ----
    {
        bf16x8 Sb[2];
#pragma unroll
        for (int kc = 0; kc < 2; ++kc)
            Sb[kc] = *(const bf16x8*)&SS[l15 * 72 + kc * 32 + quad * 8];
        f32x4 acc2[2] = {zv, zv};
#pragma unroll
        for (int c = 0; c < 4; ++c) {
            bf16x8 Ah, Al;
            split8(wva[c], wvb[c], Ah, Al);
            acc2[c >> 1] = MFMA(Ah, Sb[c & 1], acc2[c >> 1]);
            acc2[c >> 1] = MFMA(Al, Sb[c & 1], acc2[c >> 1]);
        }
#pragma unroll
        for (int et = 0; et < 2; ++et) {
            int e0 = et * 16 + quad * 4;
            float4 b = *(const float4*)&wv2b[e0];
            f32x4 a = acc2[et];
            *(float4*)&out[(size_t)(n0 + l15) * 32 + e0] =
                make_float4(a[0] + b.x, a[1] + b.y, a[2] + b.z, a[3] + b.w);
        }
    }
}

extern "C" void kernel_launch(void* const* d_in, const int* in_sizes, int n_in,
                              void* d_out, int out_size, void* d_ws, size_t ws_size,
                              hipStream_t stream) {
    const float* o     = (const float*)d_in[0];
    const float* onx   = (const float*)d_in[1];
    const float* h     = (const float*)d_in[2];
    const float* act   = (const float*)d_in[3];
    const float* wq_w  = (const float*)d_in[4];
    const float* wq_b  = (const float*)d_in[5];
    const float* wk_w  = (const float*)d_in[6];
    // d_in[7] = wk_b unused (softmax-invariant, diagonal masked)
    const float* wv1_w = (const float*)d_in[8];
    const float* wv1_b = (const float*)d_in[9];
    const float* wv2_w = (const float*)d_in[10];
    const float* wv2_b = (const float*)d_in[11];
    float* out = (float*)d_out;
    char* ws   = (char*)d_ws;   // needs ~105 KB

    k_setup<<<105, 256, 0, stream>>>(wq_w, wq_b, wk_w, wv1_w, ws);
    fused<<<4096, 64, 0, stream>>>(o, onx, h, act, wv1_b, wv2_w, wv2_b, ws, out);
}